// Round 2
// baseline (296.887 us; speedup 1.0000x reference)
//
#include <hip/hip_runtime.h>
#include <hip/hip_bf16.h>

// HierarchicalAttention: B=4,T=50,D=512, SRC=400, SENTS=16, WORDS=40.
// All float inputs are FLOAT32 (reference dtype). Output float32.
// Pipeline: k0 transpose+bf16-cast weights -> k1 MFMA projections (bf16 in, f32 out)
//           -> k2 tanh scores -> k3a masked softmax -> k3b context partials -> k4 combine.

#define B_    4
#define T_    50
#define D_    512
#define SRC_  400
#define SENTS_ 16
#define WORDS_ 40
#define NW_   640      // SENTS*WORDS
#define NMEM_ 1040     // SRC + NW
#define NJOB_ 1056     // NMEM + SENTS (score jobs per batch)

typedef unsigned short ushort_t;
using s8v = __attribute__((ext_vector_type(8))) short;   // 8 bf16 (4 VGPRs)
using f4v = __attribute__((ext_vector_type(4))) float;   // MFMA accumulator

// ---- workspace layout (float offsets) ----
#define OFF_WQ_WORD 0
#define OFF_WQ_SENT 102400
#define OFF_WQ_PASS 204800
#define OFF_UH_SRC  307200
#define OFF_UH_WORD 1126400
#define OFF_UH_SENT 2437120
#define OFF_SC_SRC  2469888
#define OFF_SC_WORD 2549888
#define OFF_SC_SENT 2677888
#define OFF_PN      2681088
#define OFF_CPART   2889088
#define WT_BYTE_OFF 13194752ull   // 3298688 floats * 4B; bf16 Wt region after

__device__ __forceinline__ ushort_t f2b(float f) {
    __hip_bfloat16 h = __float2bfloat16(f);   // RNE
    return *(ushort_t*)&h;
}

// ---------------- k0: transpose 6 f32 weight matrices W[k][n] -> bf16 Wt[n][k] ----------------
__global__ __launch_bounds__(256) void k0_transpose(
    const float* __restrict__ w0, const float* __restrict__ w1,
    const float* __restrict__ w2, const float* __restrict__ w3,
    const float* __restrict__ w4, const float* __restrict__ w5,
    ushort_t* __restrict__ wt)
{
    __shared__ float tile[32][33];
    const float* W;
    switch (blockIdx.z) {
        case 0: W = w0; break; case 1: W = w1; break; case 2: W = w2; break;
        case 3: W = w3; break; case 4: W = w4; break; default: W = w5; break;
    }
    ushort_t* Wt = wt + blockIdx.z * (D_ * D_);
    int n0 = blockIdx.x * 32, k0 = blockIdx.y * 32;
    int tx = threadIdx.x & 31, ty = threadIdx.x >> 5;
#pragma unroll
    for (int a = 0; a < 4; ++a)
        tile[ty + a * 8][tx] = W[(k0 + ty + a * 8) * D_ + n0 + tx];
    __syncthreads();
#pragma unroll
    for (int a = 0; a < 4; ++a)
        Wt[(n0 + ty + a * 8) * D_ + k0 + tx] = f2b(tile[tx][ty + a * 8]);
}

// ---------------- k1: all projections via bf16 MFMA, fp32 out to ws ----------------
// grid (8 n-tiles, 40 m-tiles, 6 segments), 256 thr. Block tile 64x64, K=512.
__global__ __launch_bounds__(256) void k1_gemm(
    const float* __restrict__ source, const float* __restrict__ src_bank,
    const float* __restrict__ qa_sent_bank, const float* __restrict__ qa_word_bank,
    const ushort_t* __restrict__ wt,
    const float* __restrict__ bq_word, const float* __restrict__ bq_sent,
    const float* __restrict__ bq_pass,
    float* __restrict__ wsf)
{
    __shared__ short At[64 * 32];
    __shared__ short Bt[64 * 32];
    int z = blockIdx.z;
    int M, atype; const float* bias; float* C;
    switch (z) {
        case 0: M = 200;  atype = 0; bias = bq_word; C = wsf + OFF_WQ_WORD; break;
        case 1: M = 200;  atype = 0; bias = bq_sent; C = wsf + OFF_WQ_SENT; break;
        case 2: M = 200;  atype = 0; bias = bq_pass; C = wsf + OFF_WQ_PASS; break;
        case 3: M = 2560; atype = 1; bias = nullptr; C = wsf + OFF_UH_WORD; break;
        case 4: M = 1600; atype = 2; bias = nullptr; C = wsf + OFF_UH_SRC;  break;
        default: M = 64;  atype = 3; bias = nullptr; C = wsf + OFF_UH_SENT; break;
    }
    int m0 = blockIdx.y * 64;
    if (m0 >= M) return;
    int n0 = blockIdx.x * 64;
    const ushort_t* W = wt + z * (D_ * D_);   // Wt: [n][k] bf16

    int tid = threadIdx.x;
    int lane = tid & 63, wv = tid >> 6;
    int quad = lane >> 4, l16 = lane & 15;
    int sm = tid >> 2, koff = (tid & 3) * 8;  // staging: row sm, 8-elem chunk koff

    // A-row gather base (row -> global f32 pointer per segment type)
    const float* arow = nullptr;
    {
        int r = m0 + sm;
        if (r < M) {
            if (atype == 0) arow = source + r * D_;
            else if (atype == 1) { int b = r / NW_; int j = r - b * NW_;
                                   int se = j / WORDS_; int wd = j - se * WORDS_;
                                   arow = qa_word_bank + ((wd * B_ + b) * SENTS_ + se) * D_; }
            else if (atype == 2) { int b = r / SRC_; int j = r - b * SRC_;
                                   arow = src_bank + (j * B_ + b) * D_; }
            else                 { int b = r >> 4; int s2 = r & 15;
                                   arow = qa_sent_bank + (s2 * B_ + b) * D_; }
        }
    }
    const ushort_t* wrow = W + (n0 + sm) * D_;

    f4v acc[4] = { {0.f,0.f,0.f,0.f}, {0.f,0.f,0.f,0.f},
                   {0.f,0.f,0.f,0.f}, {0.f,0.f,0.f,0.f} };

    for (int kk = 0; kk < 16; ++kk) {
        int k0 = kk * 32;
        union { ushort_t u[8]; int4 v; } pk;
        if (arow) {
            float4 f0 = *(const float4*)(arow + k0 + koff);
            float4 f1 = *(const float4*)(arow + k0 + koff + 4);
            pk.u[0] = f2b(f0.x); pk.u[1] = f2b(f0.y);
            pk.u[2] = f2b(f0.z); pk.u[3] = f2b(f0.w);
            pk.u[4] = f2b(f1.x); pk.u[5] = f2b(f1.y);
            pk.u[6] = f2b(f1.z); pk.u[7] = f2b(f1.w);
        } else {
            pk.v = int4{0, 0, 0, 0};
        }
        int4 bv = *(const int4*)(wrow + k0 + koff);
        *(int4*)(At + sm * 32 + koff) = pk.v;
        *(int4*)(Bt + sm * 32 + koff) = bv;
        __syncthreads();
        s8v af = *(const s8v*)(At + (wv * 16 + l16) * 32 + quad * 8);
#pragma unroll
        for (int ng = 0; ng < 4; ++ng) {
            s8v bf = *(const s8v*)(Bt + (ng * 16 + l16) * 32 + quad * 8);
            acc[ng] = __builtin_amdgcn_mfma_f32_16x16x32_bf16(af, bf, acc[ng], 0, 0, 0);
        }
        __syncthreads();
    }
    // epilogue: D col = lane&15, row = quad*4 + r (m89-verified layout)
#pragma unroll
    for (int ng = 0; ng < 4; ++ng) {
        int col = n0 + ng * 16 + l16;
        float bb = bias ? bias[col] : 0.f;
#pragma unroll
        for (int rr = 0; rr < 4; ++rr) {
            int row = m0 + wv * 16 + quad * 4 + rr;
            if (row < M) C[row * D_ + col] = acc[ng][rr] + bb;
        }
    }
}

// ---------------- k2: additive-attention scores, one wave per (b, slot) ----------------
__global__ __launch_bounds__(256) void k2_scores(
    const float* __restrict__ v_word, const float* __restrict__ v_sent,
    const float* __restrict__ v_pass, float* __restrict__ wsf)
{
    int lane = threadIdx.x & 63;
    int job = blockIdx.x * 4 + (threadIdx.x >> 6);   // 4224 jobs, exact
    int b = job / NJOB_, slot = job - b * NJOB_;
    const float* uh; const float* v; const float* wq; float* out; int ostride;
    if (slot < SRC_) {
        uh = wsf + OFF_UH_SRC + (b * SRC_ + slot) * D_;
        v = v_pass; wq = wsf + OFF_WQ_PASS + b * T_ * D_;
        out = wsf + OFF_SC_SRC + b * T_ * SRC_ + slot; ostride = SRC_;
    } else if (slot < NMEM_) {
        int j = slot - SRC_;
        uh = wsf + OFF_UH_WORD + (b * NW_ + j) * D_;
        v = v_word; wq = wsf + OFF_WQ_WORD + b * T_ * D_;
        out = wsf + OFF_SC_WORD + b * T_ * NW_ + j; ostride = NW_;
    } else {
        int s2 = slot - NMEM_;
        uh = wsf + OFF_UH_SENT + (b * SENTS_ + s2) * D_;
        v = v_sent; wq = wsf + OFF_WQ_SENT + b * T_ * D_;
        out = wsf + OFF_SC_SENT + b * T_ * SENTS_ + s2; ostride = SENTS_;
    }
    int d0 = lane * 8;
    float4 u0 = *(const float4*)(uh + d0);
    float4 u1 = *(const float4*)(uh + d0 + 4);
    float uhr[8] = {u0.x, u0.y, u0.z, u0.w, u1.x, u1.y, u1.z, u1.w};
    float4 v0 = *(const float4*)(v + d0);
    float4 v1 = *(const float4*)(v + d0 + 4);
    float vr[8] = {v0.x, v0.y, v0.z, v0.w, v1.x, v1.y, v1.z, v1.w};

    for (int t = 0; t < T_; ++t) {
        const float* wr = wq + t * D_ + d0;
        float4 w0 = *(const float4*)(wr);
        float4 w1 = *(const float4*)(wr + 4);
        float wrr[8] = {w0.x, w0.y, w0.z, w0.w, w1.x, w1.y, w1.z, w1.w};
        float s = 0.f;
#pragma unroll
        for (int j = 0; j < 8; ++j) {
            float x = wrr[j] + uhr[j];
            float e = __expf(x + x);                     // exp(2x)
            float th = 1.f - __fdividef(2.f, e + 1.f);   // tanh(x)
            s = fmaf(vr[j], th, s);
        }
#pragma unroll
        for (int off = 32; off > 0; off >>= 1)
            s += __shfl_xor(s, off, 64);
        if (lane == 0) out[t * ostride] = s;
    }
}

// ---------------- k3a: hier combine + mask + softmax, one block per (b,t) ----------------
__global__ __launch_bounds__(256) void k3a_softmax(
    const int* __restrict__ src_lengths, const int* __restrict__ qa_word_lengths,
    float* __restrict__ wsf)
{
    __shared__ float p[NMEM_];
    __shared__ float red[4];
    int tid = threadIdx.x, lane = tid & 63, wv = tid >> 6;
    int bt = blockIdx.x, b = bt / T_;
    const float* sc_src  = wsf + OFF_SC_SRC  + bt * SRC_;
    const float* sc_word = wsf + OFF_SC_WORD + bt * NW_;
    const float* sc_sent = wsf + OFF_SC_SENT + bt * SENTS_;
    int slen = src_lengths[b];
    float mx = -3.0e38f;
    for (int j = tid; j < NMEM_; j += 256) {
        float val;
        if (j < SRC_) {
            val = (j < slen) ? sc_src[j] : -1e30f;
        } else {
            int jj = j - SRC_; int se = jj / WORDS_; int wd = jj - se * WORDS_;
            float raw = sc_word[jj] * sc_sent[se];
            val = (wd < qa_word_lengths[b * SENTS_ + se]) ? raw : -1e30f;
        }
        p[j] = val;
        mx = fmaxf(mx, val);
    }
#pragma unroll
    for (int off = 32; off > 0; off >>= 1) mx = fmaxf(mx, __shfl_xor(mx, off, 64));
    if (lane == 0) red[wv] = mx;
    __syncthreads();
    mx = fmaxf(fmaxf(red[0], red[1]), fmaxf(red[2], red[3]));
    __syncthreads();
    float lsum = 0.f;
    for (int j = tid; j < NMEM_; j += 256) {
        float e = __expf(p[j] - mx);
        p[j] = e; lsum += e;
    }
#pragma unroll
    for (int off = 32; off > 0; off >>= 1) lsum += __shfl_xor(lsum, off, 64);
    if (lane == 0) red[wv] = lsum;
    __syncthreads();
    float inv = 1.f / (red[0] + red[1] + red[2] + red[3]);
    float* pn = wsf + OFF_PN + bt * NMEM_;
    for (int j = tid; j < NMEM_; j += 256) pn[j] = p[j] * inv;
}

// ---------------- k3b: context partials, grid (bt, 4 s-chunks) ----------------
__global__ __launch_bounds__(256) void k3b_context(
    const float* __restrict__ src_bank, const float* __restrict__ qa_word_bank,
    float* __restrict__ wsf)
{
    int bt = blockIdx.x, ch = blockIdx.y;
    int b = bt / T_;
    const float* pn = wsf + OFF_PN + bt * NMEM_;
    int d0 = threadIdx.x * 2;
    int s_begin, s_end;
    if (ch == 0)      { s_begin = 0;   s_end = 200;  }
    else if (ch == 1) { s_begin = 200; s_end = 400;  }
    else if (ch == 2) { s_begin = 400; s_end = 720;  }
    else              { s_begin = 720; s_end = 1040; }
    float a0 = 0.f, a1 = 0.f;
    for (int s = s_begin; s < s_end; ++s) {
        float wgt = pn[s];
        const float* mrow;
        if (s < SRC_) {
            mrow = src_bank + (s * B_ + b) * D_;
        } else {
            int jj = s - SRC_; int se = jj / WORDS_; int wd = jj - se * WORDS_;
            mrow = qa_word_bank + ((wd * B_ + b) * SENTS_ + se) * D_;
        }
        float2 m2 = *(const float2*)(mrow + d0);
        a0 = fmaf(wgt, m2.x, a0);
        a1 = fmaf(wgt, m2.y, a1);
    }
    float* cp = wsf + OFF_CPART + (ch * 200 + bt) * D_;
    cp[d0] = a0; cp[d0 + 1] = a1;
}

// ---------------- k4: sum partials, f32 out ----------------
__global__ __launch_bounds__(256) void k4_out(
    const float* __restrict__ wsf, float* __restrict__ out)
{
    int i = blockIdx.x * 256 + threadIdx.x;
    if (i >= 102400) return;
    const float* cp = wsf + OFF_CPART;
    out[i] = cp[i] + cp[102400 + i] + cp[204800 + i] + cp[307200 + i];
}

extern "C" void kernel_launch(void* const* d_in, const int* in_sizes, int n_in,
                              void* d_out, int out_size, void* d_ws, size_t ws_size,
                              hipStream_t stream)
{
    (void)in_sizes; (void)n_in; (void)out_size; (void)ws_size;
    const float* source          = (const float*)d_in[0];
    const float* src_bank        = (const float*)d_in[1];
    const int*   src_lengths     = (const int*)d_in[2];
    const float* qa_sent_bank    = (const float*)d_in[3];
    /* d_in[4] qa_sent_lengths unused (matches reference) */
    const float* qa_word_bank    = (const float*)d_in[5];
    const int*   qa_word_lengths = (const int*)d_in[6];
    const float* Wq_word = (const float*)d_in[7];
    const float* bq_word = (const float*)d_in[8];
    const float* Uc_word = (const float*)d_in[9];
    const float* v_word  = (const float*)d_in[10];
    const float* Wq_sent = (const float*)d_in[11];
    const float* bq_sent = (const float*)d_in[12];
    const float* Uc_sent = (const float*)d_in[13];
    const float* v_sent  = (const float*)d_in[14];
    const float* Wq_pass = (const float*)d_in[15];
    const float* bq_pass = (const float*)d_in[16];
    const float* Uc_pass = (const float*)d_in[17];
    const float* v_pass  = (const float*)d_in[18];

    float* wsf = (float*)d_ws;
    ushort_t* wt = (ushort_t*)((char*)d_ws + WT_BYTE_OFF);
    float* out = (float*)d_out;

    // Wt slot order must match k1 segment order:
    // 0:Wq_word 1:Wq_sent 2:Wq_pass 3:Uc_word 4:Uc_pass 5:Uc_sent
    k0_transpose<<<dim3(16, 16, 6), dim3(256), 0, stream>>>(
        Wq_word, Wq_sent, Wq_pass, Uc_word, Uc_pass, Uc_sent, wt);
    k1_gemm<<<dim3(8, 40, 6), dim3(256), 0, stream>>>(
        source, src_bank, qa_sent_bank, qa_word_bank, wt,
        bq_word, bq_sent, bq_pass, wsf);
    k2_scores<<<dim3(NJOB_), dim3(256), 0, stream>>>(v_word, v_sent, v_pass, wsf);
    k3a_softmax<<<dim3(200), dim3(256), 0, stream>>>(src_lengths, qa_word_lengths, wsf);
    k3b_context<<<dim3(200, 4), dim3(256), 0, stream>>>(src_bank, qa_word_bank, wsf);
    k4_out<<<dim3(400), dim3(256), 0, stream>>>(wsf, out);
}

// Round 3
// 224.551 us; speedup vs baseline: 1.3221x; 1.3221x over previous
//
#include <hip/hip_runtime.h>
#include <hip/hip_bf16.h>

// HierarchicalAttention: B=4,T=50,D=512, SRC=400, SENTS=16, WORDS=40.
// All float inputs are FLOAT32 (reference dtype). Output float32.
// Pipeline: k0t bank transpose (bf16 Mt[b][d][s]) -> k0 weight transpose (bf16)
//           -> k1 MFMA projections -> k2 tanh scores -> k3a masked softmax (bf16 P)
//           -> k3c MFMA context GEMM (P x M -> out).

#define B_    4
#define T_    50
#define D_    512
#define SRC_  400
#define SENTS_ 16
#define WORDS_ 40
#define NW_   640      // SENTS*WORDS
#define NMEM_ 1040     // SRC + NW
#define NK_   1056     // NMEM padded to 32*33 for MFMA K-loop
#define NJOB_ 1056     // NMEM + SENTS (score jobs per batch)

typedef unsigned short ushort_t;
using s8v = __attribute__((ext_vector_type(8))) short;   // 8 bf16 (4 VGPRs)
using f4v = __attribute__((ext_vector_type(4))) float;   // MFMA accumulator

// ---- workspace layout ----
// f32 region (float offsets):
#define OFF_WQ_WORD 0
#define OFF_WQ_SENT 102400
#define OFF_WQ_PASS 204800
#define OFF_UH_SRC  307200
#define OFF_UH_WORD 1126400
#define OFF_UH_SENT 2437120
#define OFF_SC_SRC  2469888
#define OFF_SC_WORD 2549888
#define OFF_SC_SENT 2677888
// f32 region ends at float 2681088 = byte 10724352
// bf16 regions (byte offsets):
#define P_BYTE_OFF  10724352ull   // P[b][64][1056]  bf16 = 540672 B
#define MT_BYTE_OFF 11265024ull   // Mt[b][512][1056] bf16 = 4325376 B
#define WT_BYTE_OFF 15590400ull   // Wt[6][512][512] bf16 = 3145728 B (end ~18.74 MB)

__device__ __forceinline__ ushort_t f2b(float f) {
    __hip_bfloat16 h = __float2bfloat16(f);   // RNE
    return *(ushort_t*)&h;
}

// ---------------- k0t: banks -> bf16 Mt[b][d][s], K(s)-major, zero-pad s>=1040 ----------------
__global__ __launch_bounds__(256) void k0t_bankT(
    const float* __restrict__ src_bank, const float* __restrict__ qa_word_bank,
    ushort_t* __restrict__ mt)
{
    __shared__ float tile[32][33];
    int s0 = blockIdx.x * 32, d0 = blockIdx.y * 32, b = blockIdx.z;
    int tx = threadIdx.x & 31, ty = threadIdx.x >> 5;
#pragma unroll
    for (int a = 0; a < 4; ++a) {
        int s = s0 + ty + a * 8;
        float val = 0.f;
        if (s < SRC_) {
            val = src_bank[(s * B_ + b) * D_ + d0 + tx];
        } else if (s < NMEM_) {
            int j = s - SRC_; int se = j / WORDS_; int wd = j - se * WORDS_;
            val = qa_word_bank[((wd * B_ + b) * SENTS_ + se) * D_ + d0 + tx];
        }
        tile[ty + a * 8][tx] = val;
    }
    __syncthreads();
    ushort_t* base = mt + (size_t)b * D_ * NK_;
#pragma unroll
    for (int a = 0; a < 4; ++a) {
        int d = d0 + ty + a * 8;
        base[(size_t)d * NK_ + s0 + tx] = f2b(tile[tx][ty + a * 8]);
    }
}

// ---------------- k0: transpose 6 f32 weight matrices W[k][n] -> bf16 Wt[n][k] ----------------
__global__ __launch_bounds__(256) void k0_transpose(
    const float* __restrict__ w0, const float* __restrict__ w1,
    const float* __restrict__ w2, const float* __restrict__ w3,
    const float* __restrict__ w4, const float* __restrict__ w5,
    ushort_t* __restrict__ wt)
{
    __shared__ float tile[32][33];
    const float* W;
    switch (blockIdx.z) {
        case 0: W = w0; break; case 1: W = w1; break; case 2: W = w2; break;
        case 3: W = w3; break; case 4: W = w4; break; default: W = w5; break;
    }
    ushort_t* Wt = wt + blockIdx.z * (D_ * D_);
    int n0 = blockIdx.x * 32, k0 = blockIdx.y * 32;
    int tx = threadIdx.x & 31, ty = threadIdx.x >> 5;
#pragma unroll
    for (int a = 0; a < 4; ++a)
        tile[ty + a * 8][tx] = W[(k0 + ty + a * 8) * D_ + n0 + tx];
    __syncthreads();
#pragma unroll
    for (int a = 0; a < 4; ++a)
        Wt[(n0 + ty + a * 8) * D_ + k0 + tx] = f2b(tile[tx][ty + a * 8]);
}

// ---------------- k1: all projections via bf16 MFMA, fp32 out to ws ----------------
// grid (8 n-tiles, 40 m-tiles, 6 segments), 256 thr. Block tile 64x64, K=512.
__global__ __launch_bounds__(256) void k1_gemm(
    const float* __restrict__ source, const float* __restrict__ src_bank,
    const float* __restrict__ qa_sent_bank, const float* __restrict__ qa_word_bank,
    const ushort_t* __restrict__ wt,
    const float* __restrict__ bq_word, const float* __restrict__ bq_sent,
    const float* __restrict__ bq_pass,
    float* __restrict__ wsf)
{
    __shared__ short At[64 * 32];
    __shared__ short Bt[64 * 32];
    int z = blockIdx.z;
    int M, atype; const float* bias; float* C;
    switch (z) {
        case 0: M = 200;  atype = 0; bias = bq_word; C = wsf + OFF_WQ_WORD; break;
        case 1: M = 200;  atype = 0; bias = bq_sent; C = wsf + OFF_WQ_SENT; break;
        case 2: M = 200;  atype = 0; bias = bq_pass; C = wsf + OFF_WQ_PASS; break;
        case 3: M = 2560; atype = 1; bias = nullptr; C = wsf + OFF_UH_WORD; break;
        case 4: M = 1600; atype = 2; bias = nullptr; C = wsf + OFF_UH_SRC;  break;
        default: M = 64;  atype = 3; bias = nullptr; C = wsf + OFF_UH_SENT; break;
    }
    int m0 = blockIdx.y * 64;
    if (m0 >= M) return;
    int n0 = blockIdx.x * 64;
    const ushort_t* W = wt + z * (D_ * D_);   // Wt: [n][k] bf16

    int tid = threadIdx.x;
    int lane = tid & 63, wv = tid >> 6;
    int quad = lane >> 4, l16 = lane & 15;
    int sm = tid >> 2, koff = (tid & 3) * 8;  // staging: row sm, 8-elem chunk koff

    // A-row gather base (row -> global f32 pointer per segment type)
    const float* arow = nullptr;
    {
        int r = m0 + sm;
        if (r < M) {
            if (atype == 0) arow = source + r * D_;
            else if (atype == 1) { int b = r / NW_; int j = r - b * NW_;
                                   int se = j / WORDS_; int wd = j - se * WORDS_;
                                   arow = qa_word_bank + ((wd * B_ + b) * SENTS_ + se) * D_; }
            else if (atype == 2) { int b = r / SRC_; int j = r - b * SRC_;
                                   arow = src_bank + (j * B_ + b) * D_; }
            else                 { int b = r >> 4; int s2 = r & 15;
                                   arow = qa_sent_bank + (s2 * B_ + b) * D_; }
        }
    }
    const ushort_t* wrow = W + (n0 + sm) * D_;

    f4v acc[4] = { {0.f,0.f,0.f,0.f}, {0.f,0.f,0.f,0.f},
                   {0.f,0.f,0.f,0.f}, {0.f,0.f,0.f,0.f} };

    for (int kk = 0; kk < 16; ++kk) {
        int k0 = kk * 32;
        union { ushort_t u[8]; int4 v; } pk;
        if (arow) {
            float4 f0 = *(const float4*)(arow + k0 + koff);
            float4 f1 = *(const float4*)(arow + k0 + koff + 4);
            pk.u[0] = f2b(f0.x); pk.u[1] = f2b(f0.y);
            pk.u[2] = f2b(f0.z); pk.u[3] = f2b(f0.w);
            pk.u[4] = f2b(f1.x); pk.u[5] = f2b(f1.y);
            pk.u[6] = f2b(f1.z); pk.u[7] = f2b(f1.w);
        } else {
            pk.v = int4{0, 0, 0, 0};
        }
        int4 bv = *(const int4*)(wrow + k0 + koff);
        *(int4*)(At + sm * 32 + koff) = pk.v;
        *(int4*)(Bt + sm * 32 + koff) = bv;
        __syncthreads();
        s8v af = *(const s8v*)(At + (wv * 16 + l16) * 32 + quad * 8);
#pragma unroll
        for (int ng = 0; ng < 4; ++ng) {
            s8v bf = *(const s8v*)(Bt + (ng * 16 + l16) * 32 + quad * 8);
            acc[ng] = __builtin_amdgcn_mfma_f32_16x16x32_bf16(af, bf, acc[ng], 0, 0, 0);
        }
        __syncthreads();
    }
    // epilogue: D col = lane&15, row = quad*4 + r (m89-verified layout)
#pragma unroll
    for (int ng = 0; ng < 4; ++ng) {
        int col = n0 + ng * 16 + l16;
        float bb = bias ? bias[col] : 0.f;
#pragma unroll
        for (int rr = 0; rr < 4; ++rr) {
            int row = m0 + wv * 16 + quad * 4 + rr;
            if (row < M) C[row * D_ + col] = acc[ng][rr] + bb;
        }
    }
}

// ---------------- k2: additive-attention scores, one wave per (b, slot) ----------------
__global__ __launch_bounds__(256) void k2_scores(
    const float* __restrict__ v_word, const float* __restrict__ v_sent,
    const float* __restrict__ v_pass, float* __restrict__ wsf)
{
    int lane = threadIdx.x & 63;
    int job = blockIdx.x * 4 + (threadIdx.x >> 6);   // 4224 jobs, exact
    int b = job / NJOB_, slot = job - b * NJOB_;
    const float* uh; const float* v; const float* wq; float* out; int ostride;
    if (slot < SRC_) {
        uh = wsf + OFF_UH_SRC + (b * SRC_ + slot) * D_;
        v = v_pass; wq = wsf + OFF_WQ_PASS + b * T_ * D_;
        out = wsf + OFF_SC_SRC + b * T_ * SRC_ + slot; ostride = SRC_;
    } else if (slot < NMEM_) {
        int j = slot - SRC_;
        uh = wsf + OFF_UH_WORD + (b * NW_ + j) * D_;
        v = v_word; wq = wsf + OFF_WQ_WORD + b * T_ * D_;
        out = wsf + OFF_SC_WORD + b * T_ * NW_ + j; ostride = NW_;
    } else {
        int s2 = slot - NMEM_;
        uh = wsf + OFF_UH_SENT + (b * SENTS_ + s2) * D_;
        v = v_sent; wq = wsf + OFF_WQ_SENT + b * T_ * D_;
        out = wsf + OFF_SC_SENT + b * T_ * SENTS_ + s2; ostride = SENTS_;
    }
    int d0 = lane * 8;
    float4 u0 = *(const float4*)(uh + d0);
    float4 u1 = *(const float4*)(uh + d0 + 4);
    float uhr[8] = {u0.x, u0.y, u0.z, u0.w, u1.x, u1.y, u1.z, u1.w};
    float4 v0 = *(const float4*)(v + d0);
    float4 v1 = *(const float4*)(v + d0 + 4);
    float vr[8] = {v0.x, v0.y, v0.z, v0.w, v1.x, v1.y, v1.z, v1.w};

    for (int t = 0; t < T_; ++t) {
        const float* wr = wq + t * D_ + d0;
        float4 w0 = *(const float4*)(wr);
        float4 w1 = *(const float4*)(wr + 4);
        float wrr[8] = {w0.x, w0.y, w0.z, w0.w, w1.x, w1.y, w1.z, w1.w};
        float s = 0.f;
#pragma unroll
        for (int j = 0; j < 8; ++j) {
            float x = wrr[j] + uhr[j];
            float e = __expf(x + x);                     // exp(2x)
            float th = 1.f - __fdividef(2.f, e + 1.f);   // tanh(x)
            s = fmaf(vr[j], th, s);
        }
#pragma unroll
        for (int off = 32; off > 0; off >>= 1)
            s += __shfl_xor(s, off, 64);
        if (lane == 0) out[t * ostride] = s;
    }
}

// ---------------- k3a: hier combine + mask + softmax -> bf16 P[b][64][1056] ----------------
__global__ __launch_bounds__(256) void k3a_softmax(
    const int* __restrict__ src_lengths, const int* __restrict__ qa_word_lengths,
    const float* __restrict__ wsf, ushort_t* __restrict__ P)
{
    __shared__ float p[NMEM_];
    __shared__ float red[4];
    int tid = threadIdx.x, lane = tid & 63, wv = tid >> 6;
    int bt = blockIdx.x, b = bt / T_, t = bt - b * T_;
    const float* sc_src  = wsf + OFF_SC_SRC  + bt * SRC_;
    const float* sc_word = wsf + OFF_SC_WORD + bt * NW_;
    const float* sc_sent = wsf + OFF_SC_SENT + bt * SENTS_;
    int slen = src_lengths[b];
    float mx = -3.0e38f;
    for (int j = tid; j < NMEM_; j += 256) {
        float val;
        if (j < SRC_) {
            val = (j < slen) ? sc_src[j] : -1e30f;
        } else {
            int jj = j - SRC_; int se = jj / WORDS_; int wd = jj - se * WORDS_;
            float raw = sc_word[jj] * sc_sent[se];
            val = (wd < qa_word_lengths[b * SENTS_ + se]) ? raw : -1e30f;
        }
        p[j] = val;
        mx = fmaxf(mx, val);
    }
#pragma unroll
    for (int off = 32; off > 0; off >>= 1) mx = fmaxf(mx, __shfl_xor(mx, off, 64));
    if (lane == 0) red[wv] = mx;
    __syncthreads();
    mx = fmaxf(fmaxf(red[0], red[1]), fmaxf(red[2], red[3]));
    __syncthreads();
    float lsum = 0.f;
    for (int j = tid; j < NMEM_; j += 256) {
        float e = __expf(p[j] - mx);
        p[j] = e; lsum += e;
    }
#pragma unroll
    for (int off = 32; off > 0; off >>= 1) lsum += __shfl_xor(lsum, off, 64);
    if (lane == 0) red[wv] = lsum;
    __syncthreads();
    float inv = 1.f / (red[0] + red[1] + red[2] + red[3]);
    ushort_t* prow = P + (size_t)(b * 64 + t) * NK_;
    for (int j = tid; j < NK_; j += 256)
        prow[j] = (j < NMEM_) ? f2b(p[j] * inv) : (ushort_t)0;
}

// ---------------- k3c: context GEMM  C[b][t][d] = sum_s P[t,s] * Mt[d,s] ----------------
// grid (8 d-tiles, 4 b), 256 thr. Tile 64x64, K=1056.
__global__ __launch_bounds__(256) void k3c_gemm(
    const ushort_t* __restrict__ P, const ushort_t* __restrict__ Mt,
    float* __restrict__ out)
{
    __shared__ short At[64 * 32];
    __shared__ short Bt[64 * 32];
    int b = blockIdx.y;
    int n0 = blockIdx.x * 64;
    int tid = threadIdx.x;
    int lane = tid & 63, wv = tid >> 6;
    int quad = lane >> 4, l16 = lane & 15;
    int sm = tid >> 2, koff = (tid & 3) * 8;

    const ushort_t* arow = (sm < T_) ? (P + (size_t)(b * 64 + sm) * NK_ + koff) : nullptr;
    const ushort_t* brow = Mt + ((size_t)(b * D_ + n0 + sm)) * NK_ + koff;

    f4v acc[4] = { {0.f,0.f,0.f,0.f}, {0.f,0.f,0.f,0.f},
                   {0.f,0.f,0.f,0.f}, {0.f,0.f,0.f,0.f} };

    for (int kk = 0; kk < 33; ++kk) {
        int k0 = kk * 32;
        int4 av = int4{0, 0, 0, 0};
        if (arow) av = *(const int4*)(arow + k0);
        int4 bv = *(const int4*)(brow + k0);
        *(int4*)(At + sm * 32 + koff) = av;
        *(int4*)(Bt + sm * 32 + koff) = bv;
        __syncthreads();
        s8v af = *(const s8v*)(At + (wv * 16 + l16) * 32 + quad * 8);
#pragma unroll
        for (int ng = 0; ng < 4; ++ng) {
            s8v bf = *(const s8v*)(Bt + (ng * 16 + l16) * 32 + quad * 8);
            acc[ng] = __builtin_amdgcn_mfma_f32_16x16x32_bf16(af, bf, acc[ng], 0, 0, 0);
        }
        __syncthreads();
    }
#pragma unroll
    for (int ng = 0; ng < 4; ++ng) {
        int col = n0 + ng * 16 + l16;
#pragma unroll
        for (int rr = 0; rr < 4; ++rr) {
            int row = wv * 16 + quad * 4 + rr;   // t
            if (row < T_) out[(size_t)(b * T_ + row) * D_ + col] = acc[ng][rr];
        }
    }
}

extern "C" void kernel_launch(void* const* d_in, const int* in_sizes, int n_in,
                              void* d_out, int out_size, void* d_ws, size_t ws_size,
                              hipStream_t stream)
{
    (void)in_sizes; (void)n_in; (void)out_size; (void)ws_size;
    const float* source          = (const float*)d_in[0];
    const float* src_bank        = (const float*)d_in[1];
    const int*   src_lengths     = (const int*)d_in[2];
    const float* qa_sent_bank    = (const float*)d_in[3];
    /* d_in[4] qa_sent_lengths unused (matches reference) */
    const float* qa_word_bank    = (const float*)d_in[5];
    const int*   qa_word_lengths = (const int*)d_in[6];
    const float* Wq_word = (const float*)d_in[7];
    const float* bq_word = (const float*)d_in[8];
    const float* Uc_word = (const float*)d_in[9];
    const float* v_word  = (const float*)d_in[10];
    const float* Wq_sent = (const float*)d_in[11];
    const float* bq_sent = (const float*)d_in[12];
    const float* Uc_sent = (const float*)d_in[13];
    const float* v_sent  = (const float*)d_in[14];
    const float* Wq_pass = (const float*)d_in[15];
    const float* bq_pass = (const float*)d_in[16];
    const float* Uc_pass = (const float*)d_in[17];
    const float* v_pass  = (const float*)d_in[18];

    float* wsf = (float*)d_ws;
    ushort_t* Pb  = (ushort_t*)((char*)d_ws + P_BYTE_OFF);
    ushort_t* mt  = (ushort_t*)((char*)d_ws + MT_BYTE_OFF);
    ushort_t* wt  = (ushort_t*)((char*)d_ws + WT_BYTE_OFF);
    float* out = (float*)d_out;

    k0t_bankT<<<dim3(33, 16, 4), dim3(256), 0, stream>>>(src_bank, qa_word_bank, mt);
    // Wt slot order must match k1 segment order:
    // 0:Wq_word 1:Wq_sent 2:Wq_pass 3:Uc_word 4:Uc_pass 5:Uc_sent
    k0_transpose<<<dim3(16, 16, 6), dim3(256), 0, stream>>>(
        Wq_word, Wq_sent, Wq_pass, Uc_word, Uc_pass, Uc_sent, wt);
    k1_gemm<<<dim3(8, 40, 6), dim3(256), 0, stream>>>(
        source, src_bank, qa_sent_bank, qa_word_bank, wt,
        bq_word, bq_sent, bq_pass, wsf);
    k2_scores<<<dim3(NJOB_), dim3(256), 0, stream>>>(v_word, v_sent, v_pass, wsf);
    k3a_softmax<<<dim3(200), dim3(256), 0, stream>>>(src_lengths, qa_word_lengths, wsf, Pb);
    k3c_gemm<<<dim3(8, 4), dim3(256), 0, stream>>>(Pb, mt, out);
}

// Round 4
// 176.922 us; speedup vs baseline: 1.6781x; 1.2692x over previous
//
#include <hip/hip_runtime.h>
#include <hip/hip_bf16.h>

// HierarchicalAttention: B=4,T=50,D=512, SRC=400, SENTS=16, WORDS=40.
// All float inputs are FLOAT32 (reference dtype). Output float32.
// Pipeline: k0t bank transpose (bf16 Mt[b][d][s]) -> k0 weight transpose (bf16)
//           -> k1 MFMA projections (outputs pre-scaled by 2*log2e for k2)
//           -> k2 tanh scores (sigmoid form, chunked batched reduction)
//           -> k3a masked softmax (bf16 P) -> k3c MFMA context GEMM.

#define B_    4
#define T_    50
#define D_    512
#define SRC_  400
#define SENTS_ 16
#define WORDS_ 40
#define NW_   640      // SENTS*WORDS
#define NMEM_ 1040     // SRC + NW
#define NK_   1056     // NMEM padded to 32*33 for MFMA K-loop
#define NJOB_ 1056     // NMEM + SENTS (score jobs per batch)

#define C2L2E 2.8853900817779268f   // 2*log2(e): x -> exp2(C2L2E*x) = exp(2x)

typedef unsigned short ushort_t;
using s8v = __attribute__((ext_vector_type(8))) short;   // 8 bf16 (4 VGPRs)
using f4v = __attribute__((ext_vector_type(4))) float;   // MFMA accumulator

// ---- workspace layout ----
// f32 region (float offsets):
#define OFF_WQ_WORD 0
#define OFF_WQ_SENT 102400
#define OFF_WQ_PASS 204800
#define OFF_UH_SRC  307200
#define OFF_UH_WORD 1126400
#define OFF_UH_SENT 2437120
#define OFF_SC_SRC  2469888
#define OFF_SC_WORD 2549888
#define OFF_SC_SENT 2677888
// f32 region ends at float 2681088 = byte 10724352
// bf16 regions (byte offsets):
#define P_BYTE_OFF  10724352ull   // P[b][64][1056]  bf16 = 540672 B
#define MT_BYTE_OFF 11265024ull   // Mt[b][512][1056] bf16 = 4325376 B
#define WT_BYTE_OFF 15590400ull   // Wt[6][512][512] bf16 = 3145728 B (end ~18.74 MB)

__device__ __forceinline__ ushort_t f2b(float f) {
    __hip_bfloat16 h = __float2bfloat16(f);   // RNE
    return *(ushort_t*)&h;
}

// ---------------- k0t: banks -> bf16 Mt[b][d][s], K(s)-major, zero-pad s>=1040 ----------------
__global__ __launch_bounds__(256) void k0t_bankT(
    const float* __restrict__ src_bank, const float* __restrict__ qa_word_bank,
    ushort_t* __restrict__ mt)
{
    __shared__ float tile[32][33];
    int s0 = blockIdx.x * 32, d0 = blockIdx.y * 32, b = blockIdx.z;
    int tx = threadIdx.x & 31, ty = threadIdx.x >> 5;
#pragma unroll
    for (int a = 0; a < 4; ++a) {
        int s = s0 + ty + a * 8;
        float val = 0.f;
        if (s < SRC_) {
            val = src_bank[(s * B_ + b) * D_ + d0 + tx];
        } else if (s < NMEM_) {
            int j = s - SRC_; int se = j / WORDS_; int wd = j - se * WORDS_;
            val = qa_word_bank[((wd * B_ + b) * SENTS_ + se) * D_ + d0 + tx];
        }
        tile[ty + a * 8][tx] = val;
    }
    __syncthreads();
    ushort_t* base = mt + (size_t)b * D_ * NK_;
#pragma unroll
    for (int a = 0; a < 4; ++a) {
        int d = d0 + ty + a * 8;
        base[(size_t)d * NK_ + s0 + tx] = f2b(tile[tx][ty + a * 8]);
    }
}

// ---------------- k0: transpose 6 f32 weight matrices W[k][n] -> bf16 Wt[n][k] ----------------
__global__ __launch_bounds__(256) void k0_transpose(
    const float* __restrict__ w0, const float* __restrict__ w1,
    const float* __restrict__ w2, const float* __restrict__ w3,
    const float* __restrict__ w4, const float* __restrict__ w5,
    ushort_t* __restrict__ wt)
{
    __shared__ float tile[32][33];
    const float* W;
    switch (blockIdx.z) {
        case 0: W = w0; break; case 1: W = w1; break; case 2: W = w2; break;
        case 3: W = w3; break; case 4: W = w4; break; default: W = w5; break;
    }
    ushort_t* Wt = wt + blockIdx.z * (D_ * D_);
    int n0 = blockIdx.x * 32, k0 = blockIdx.y * 32;
    int tx = threadIdx.x & 31, ty = threadIdx.x >> 5;
#pragma unroll
    for (int a = 0; a < 4; ++a)
        tile[ty + a * 8][tx] = W[(k0 + ty + a * 8) * D_ + n0 + tx];
    __syncthreads();
#pragma unroll
    for (int a = 0; a < 4; ++a)
        Wt[(n0 + ty + a * 8) * D_ + k0 + tx] = f2b(tile[tx][ty + a * 8]);
}

// ---------------- k1: all projections via bf16 MFMA, fp32*C2L2E out to ws ----------------
// grid (8 n-tiles, 40 m-tiles, 6 segments), 256 thr. Block tile 64x64, K=512.
__global__ __launch_bounds__(256) void k1_gemm(
    const float* __restrict__ source, const float* __restrict__ src_bank,
    const float* __restrict__ qa_sent_bank, const float* __restrict__ qa_word_bank,
    const ushort_t* __restrict__ wt,
    const float* __restrict__ bq_word, const float* __restrict__ bq_sent,
    const float* __restrict__ bq_pass,
    float* __restrict__ wsf)
{
    __shared__ short At[64 * 32];
    __shared__ short Bt[64 * 32];
    int z = blockIdx.z;
    int M, atype; const float* bias; float* C;
    switch (z) {
        case 0: M = 200;  atype = 0; bias = bq_word; C = wsf + OFF_WQ_WORD; break;
        case 1: M = 200;  atype = 0; bias = bq_sent; C = wsf + OFF_WQ_SENT; break;
        case 2: M = 200;  atype = 0; bias = bq_pass; C = wsf + OFF_WQ_PASS; break;
        case 3: M = 2560; atype = 1; bias = nullptr; C = wsf + OFF_UH_WORD; break;
        case 4: M = 1600; atype = 2; bias = nullptr; C = wsf + OFF_UH_SRC;  break;
        default: M = 64;  atype = 3; bias = nullptr; C = wsf + OFF_UH_SENT; break;
    }
    int m0 = blockIdx.y * 64;
    if (m0 >= M) return;
    int n0 = blockIdx.x * 64;
    const ushort_t* W = wt + z * (D_ * D_);   // Wt: [n][k] bf16

    int tid = threadIdx.x;
    int lane = tid & 63, wv = tid >> 6;
    int quad = lane >> 4, l16 = lane & 15;
    int sm = tid >> 2, koff = (tid & 3) * 8;  // staging: row sm, 8-elem chunk koff

    // A-row gather base (row -> global f32 pointer per segment type)
    const float* arow = nullptr;
    {
        int r = m0 + sm;
        if (r < M) {
            if (atype == 0) arow = source + r * D_;
            else if (atype == 1) { int b = r / NW_; int j = r - b * NW_;
                                   int se = j / WORDS_; int wd = j - se * WORDS_;
                                   arow = qa_word_bank + ((wd * B_ + b) * SENTS_ + se) * D_; }
            else if (atype == 2) { int b = r / SRC_; int j = r - b * SRC_;
                                   arow = src_bank + (j * B_ + b) * D_; }
            else                 { int b = r >> 4; int s2 = r & 15;
                                   arow = qa_sent_bank + (s2 * B_ + b) * D_; }
        }
    }
    const ushort_t* wrow = W + (n0 + sm) * D_;

    f4v acc[4] = { {0.f,0.f,0.f,0.f}, {0.f,0.f,0.f,0.f},
                   {0.f,0.f,0.f,0.f}, {0.f,0.f,0.f,0.f} };

    for (int kk = 0; kk < 16; ++kk) {
        int k0 = kk * 32;
        union { ushort_t u[8]; int4 v; } pk;
        if (arow) {
            float4 f0 = *(const float4*)(arow + k0 + koff);
            float4 f1 = *(const float4*)(arow + k0 + koff + 4);
            pk.u[0] = f2b(f0.x); pk.u[1] = f2b(f0.y);
            pk.u[2] = f2b(f0.z); pk.u[3] = f2b(f0.w);
            pk.u[4] = f2b(f1.x); pk.u[5] = f2b(f1.y);
            pk.u[6] = f2b(f1.z); pk.u[7] = f2b(f1.w);
        } else {
            pk.v = int4{0, 0, 0, 0};
        }
        int4 bv = *(const int4*)(wrow + k0 + koff);
        *(int4*)(At + sm * 32 + koff) = pk.v;
        *(int4*)(Bt + sm * 32 + koff) = bv;
        __syncthreads();
        s8v af = *(const s8v*)(At + (wv * 16 + l16) * 32 + quad * 8);
#pragma unroll
        for (int ng = 0; ng < 4; ++ng) {
            s8v bf = *(const s8v*)(Bt + (ng * 16 + l16) * 32 + quad * 8);
            acc[ng] = __builtin_amdgcn_mfma_f32_16x16x32_bf16(af, bf, acc[ng], 0, 0, 0);
        }
        __syncthreads();
    }
    // epilogue: D col = lane&15, row = quad*4 + r. Pre-scale by 2*log2e so
    // k2 can use exp2 directly: stored value = (acc+bias) * C2L2E.
#pragma unroll
    for (int ng = 0; ng < 4; ++ng) {
        int col = n0 + ng * 16 + l16;
        float bb = bias ? bias[col] : 0.f;
#pragma unroll
        for (int rr = 0; rr < 4; ++rr) {
            int row = m0 + wv * 16 + quad * 4 + rr;
            if (row < M) C[row * D_ + col] = (acc[ng][rr] + bb) * C2L2E;
        }
    }
}

// ---------------- k2: additive-attention scores, one wave per (b, slot) ----------------
// score = Vsum - 2 * sum_d v[d]*sigmoid(-2x) ; exp(2x) = exp2(scaled w' + u').
// t processed in chunks of 10: 10 independent butterfly chains overlap.
__global__ __launch_bounds__(256) void k2_scores(
    const float* __restrict__ v_word, const float* __restrict__ v_sent,
    const float* __restrict__ v_pass, float* __restrict__ wsf)
{
    int lane = threadIdx.x & 63;
    int job = blockIdx.x * 4 + (threadIdx.x >> 6);   // 4224 jobs, exact
    int b = job / NJOB_, slot = job - b * NJOB_;
    const float* uh; const float* v; const float* wq; float* out; int ostride;
    if (slot < SRC_) {
        uh = wsf + OFF_UH_SRC + (b * SRC_ + slot) * D_;
        v = v_pass; wq = wsf + OFF_WQ_PASS + b * T_ * D_;
        out = wsf + OFF_SC_SRC + b * T_ * SRC_ + slot; ostride = SRC_;
    } else if (slot < NMEM_) {
        int j = slot - SRC_;
        uh = wsf + OFF_UH_WORD + (b * NW_ + j) * D_;
        v = v_word; wq = wsf + OFF_WQ_WORD + b * T_ * D_;
        out = wsf + OFF_SC_WORD + b * T_ * NW_ + j; ostride = NW_;
    } else {
        int s2 = slot - NMEM_;
        uh = wsf + OFF_UH_SENT + (b * SENTS_ + s2) * D_;
        v = v_sent; wq = wsf + OFF_WQ_SENT + b * T_ * D_;
        out = wsf + OFF_SC_SENT + b * T_ * SENTS_ + s2; ostride = SENTS_;
    }
    int d0 = lane * 8;
    float4 u0 = *(const float4*)(uh + d0);
    float4 u1 = *(const float4*)(uh + d0 + 4);
    float uhr[8] = {u0.x, u0.y, u0.z, u0.w, u1.x, u1.y, u1.z, u1.w};
    float4 v0 = *(const float4*)(v + d0);
    float4 v1 = *(const float4*)(v + d0 + 4);
    float vr[8] = {v0.x, v0.y, v0.z, v0.w, v1.x, v1.y, v1.z, v1.w};

    // Vsum = sum_d v[d] (broadcast to all lanes)
    float vs = ((vr[0] + vr[1]) + (vr[2] + vr[3])) + ((vr[4] + vr[5]) + (vr[6] + vr[7]));
#pragma unroll
    for (int off = 32; off > 0; off >>= 1) vs += __shfl_xor(vs, off, 64);

    for (int tc = 0; tc < T_; tc += 10) {
        float acc[10];
#pragma unroll
        for (int u = 0; u < 10; ++u) {
            const float* wr = wq + (tc + u) * D_ + d0;
            float4 w0 = *(const float4*)(wr);
            float4 w1 = *(const float4*)(wr + 4);
            float wrr[8] = {w0.x, w0.y, w0.z, w0.w, w1.x, w1.y, w1.z, w1.w};
            float a = 0.f;
#pragma unroll
            for (int j = 0; j < 8; ++j) {
                float e = __builtin_amdgcn_exp2f(wrr[j] + uhr[j]);  // exp(2x)
                float r = __builtin_amdgcn_rcpf(e + 1.f);           // sigmoid(-2x)
                a = fmaf(vr[j], r, a);
            }
            acc[u] = a;
        }
        // 10 independent butterfly reductions (latency overlapped)
#pragma unroll
        for (int off = 32; off > 0; off >>= 1) {
#pragma unroll
            for (int u = 0; u < 10; ++u)
                acc[u] += __shfl_xor(acc[u], off, 64);
        }
        if (lane == 0) {
#pragma unroll
            for (int u = 0; u < 10; ++u)
                out[(tc + u) * ostride] = fmaf(-2.f, acc[u], vs);
        }
    }
}

// ---------------- k3a: hier combine + mask + softmax -> bf16 P[b][64][1056] ----------------
__global__ __launch_bounds__(256) void k3a_softmax(
    const int* __restrict__ src_lengths, const int* __restrict__ qa_word_lengths,
    const float* __restrict__ wsf, ushort_t* __restrict__ P)
{
    __shared__ float p[NMEM_];
    __shared__ float red[4];
    int tid = threadIdx.x, lane = tid & 63, wv = tid >> 6;
    int bt = blockIdx.x, b = bt / T_, t = bt - b * T_;
    const float* sc_src  = wsf + OFF_SC_SRC  + bt * SRC_;
    const float* sc_word = wsf + OFF_SC_WORD + bt * NW_;
    const float* sc_sent = wsf + OFF_SC_SENT + bt * SENTS_;
    int slen = src_lengths[b];
    float mx = -3.0e38f;
    for (int j = tid; j < NMEM_; j += 256) {
        float val;
        if (j < SRC_) {
            val = (j < slen) ? sc_src[j] : -1e30f;
        } else {
            int jj = j - SRC_; int se = jj / WORDS_; int wd = jj - se * WORDS_;
            float raw = sc_word[jj] * sc_sent[se];
            val = (wd < qa_word_lengths[b * SENTS_ + se]) ? raw : -1e30f;
        }
        p[j] = val;
        mx = fmaxf(mx, val);
    }
#pragma unroll
    for (int off = 32; off > 0; off >>= 1) mx = fmaxf(mx, __shfl_xor(mx, off, 64));
    if (lane == 0) red[wv] = mx;
    __syncthreads();
    mx = fmaxf(fmaxf(red[0], red[1]), fmaxf(red[2], red[3]));
    __syncthreads();
    float lsum = 0.f;
    for (int j = tid; j < NMEM_; j += 256) {
        float e = __expf(p[j] - mx);
        p[j] = e; lsum += e;
    }
#pragma unroll
    for (int off = 32; off > 0; off >>= 1) lsum += __shfl_xor(lsum, off, 64);
    if (lane == 0) red[wv] = lsum;
    __syncthreads();
    float inv = 1.f / (red[0] + red[1] + red[2] + red[3]);
    ushort_t* prow = P + (size_t)(b * 64 + t) * NK_;
    for (int j = tid; j < NK_; j += 256)
        prow[j] = (j < NMEM_) ? f2b(p[j] * inv) : (ushort_t)0;
}

// ---------------- k3c: context GEMM  C[b][t][d] = sum_s P[t,s] * Mt[d,s] ----------------
// grid (8 d-tiles, 4 b), 256 thr. Tile 64x64, K=1056.
__global__ __launch_bounds__(256) void k3c_gemm(
    const ushort_t* __restrict__ P, const ushort_t* __restrict__ Mt,
    float* __restrict__ out)
{
    __shared__ short At[64 * 32];
    __shared__ short Bt[64 * 32];
    int b = blockIdx.y;
    int n0 = blockIdx.x * 64;
    int tid = threadIdx.x;
    int lane = tid & 63, wv = tid >> 6;
    int quad = lane >> 4, l16 = lane & 15;
    int sm = tid >> 2, koff = (tid & 3) * 8;

    const ushort_t* arow = (sm < T_) ? (P + (size_t)(b * 64 + sm) * NK_ + koff) : nullptr;
    const ushort_t* brow = Mt + ((size_t)(b * D_ + n0 + sm)) * NK_ + koff;

    f4v acc[4] = { {0.f,0.f,0.f,0.f}, {0.f,0.f,0.f,0.f},
                   {0.f,0.f,0.f,0.f}, {0.f,0.f,0.f,0.f} };

    for (int kk = 0; kk < 33; ++kk) {
        int k0 = kk * 32;
        int4 av = int4{0, 0, 0, 0};
        if (arow) av = *(const int4*)(arow + k0);
        int4 bv = *(const int4*)(brow + k0);
        *(int4*)(At + sm * 32 + koff) = av;
        *(int4*)(Bt + sm * 32 + koff) = bv;
        __syncthreads();
        s8v af = *(const s8v*)(At + (wv * 16 + l16) * 32 + quad * 8);
#pragma unroll
        for (int ng = 0; ng < 4; ++ng) {
            s8v bf = *(const s8v*)(Bt + (ng * 16 + l16) * 32 + quad * 8);
            acc[ng] = __builtin_amdgcn_mfma_f32_16x16x32_bf16(af, bf, acc[ng], 0, 0, 0);
        }
        __syncthreads();
    }
#pragma unroll
    for (int ng = 0; ng < 4; ++ng) {
        int col = n0 + ng * 16 + l16;
#pragma unroll
        for (int rr = 0; rr < 4; ++rr) {
            int row = wv * 16 + quad * 4 + rr;   // t
            if (row < T_) out[(size_t)(b * T_ + row) * D_ + col] = acc[ng][rr];
        }
    }
}

extern "C" void kernel_launch(void* const* d_in, const int* in_sizes, int n_in,
                              void* d_out, int out_size, void* d_ws, size_t ws_size,
                              hipStream_t stream)
{
    (void)in_sizes; (void)n_in; (void)out_size; (void)ws_size;
    const float* source          = (const float*)d_in[0];
    const float* src_bank        = (const float*)d_in[1];
    const int*   src_lengths     = (const int*)d_in[2];
    const float* qa_sent_bank    = (const float*)d_in[3];
    /* d_in[4] qa_sent_lengths unused (matches reference) */
    const float* qa_word_bank    = (const float*)d_in[5];
    const int*   qa_word_lengths = (const int*)d_in[6];
    const float* Wq_word = (const float*)d_in[7];
    const float* bq_word = (const float*)d_in[8];
    const float* Uc_word = (const float*)d_in[9];
    const float* v_word  = (const float*)d_in[10];
    const float* Wq_sent = (const float*)d_in[11];
    const float* bq_sent = (const float*)d_in[12];
    const float* Uc_sent = (const float*)d_in[13];
    const float* v_sent  = (const float*)d_in[14];
    const float* Wq_pass = (const float*)d_in[15];
    const float* bq_pass = (const float*)d_in[16];
    const float* Uc_pass = (const float*)d_in[17];
    const float* v_pass  = (const float*)d_in[18];

    float* wsf = (float*)d_ws;
    ushort_t* Pb  = (ushort_t*)((char*)d_ws + P_BYTE_OFF);
    ushort_t* mt  = (ushort_t*)((char*)d_ws + MT_BYTE_OFF);
    ushort_t* wt  = (ushort_t*)((char*)d_ws + WT_BYTE_OFF);
    float* out = (float*)d_out;

    k0t_bankT<<<dim3(33, 16, 4), dim3(256), 0, stream>>>(src_bank, qa_word_bank, mt);
    // Wt slot order must match k1 segment order:
    // 0:Wq_word 1:Wq_sent 2:Wq_pass 3:Uc_word 4:Uc_pass 5:Uc_sent
    k0_transpose<<<dim3(16, 16, 6), dim3(256), 0, stream>>>(
        Wq_word, Wq_sent, Wq_pass, Uc_word, Uc_pass, Uc_sent, wt);
    k1_gemm<<<dim3(8, 40, 6), dim3(256), 0, stream>>>(
        source, src_bank, qa_sent_bank, qa_word_bank, wt,
        bq_word, bq_sent, bq_pass, wsf);
    k2_scores<<<dim3(NJOB_), dim3(256), 0, stream>>>(v_word, v_sent, v_pass, wsf);
    k3a_softmax<<<dim3(200), dim3(256), 0, stream>>>(src_lengths, qa_word_lengths, wsf, Pb);
    k3c_gemm<<<dim3(8, 4), dim3(256), 0, stream>>>(Pb, mt, out);
}

// Round 5
// 166.272 us; speedup vs baseline: 1.7856x; 1.0641x over previous
//
#include <hip/hip_runtime.h>
#include <hip/hip_bf16.h>

// HierarchicalAttention: B=4,T=50,D=512, SRC=400, SENTS=16, WORDS=40.
// All float inputs are FLOAT32 (reference dtype). Output float32.
// Pipeline (5 launches):
//   k0f  fused transposes: weights W[k][n]->bf16 Wt[n][k], banks->bf16 Mt[b][d][s]
//   k1   MFMA projections (outputs pre-scaled by 2*log2e for k2)
//   k2   tanh scores (sigmoid form; masked jobs skipped; 2 waves/job)
//   k3a  hier combine + mask + softmax -> bf16 P
//   k3c  MFMA context GEMM (P x M -> out)

#define B_    4
#define T_    50
#define D_    512
#define SRC_  400
#define SENTS_ 16
#define WORDS_ 40
#define NW_   640      // SENTS*WORDS
#define NMEM_ 1040     // SRC + NW
#define NK_   1056     // NMEM padded to 32*33 for MFMA K-loop
#define NJOB_ 1056     // NMEM + SENTS (score jobs per batch)

#define C2L2E 2.8853900817779268f   // 2*log2(e): x -> exp2(C2L2E*x) = exp(2x)

typedef unsigned short ushort_t;
using s8v = __attribute__((ext_vector_type(8))) short;   // 8 bf16 (4 VGPRs)
using f4v = __attribute__((ext_vector_type(4))) float;   // MFMA accumulator

// ---- workspace layout ----
// f32 region (float offsets):
#define OFF_WQ_WORD 0
#define OFF_WQ_SENT 102400
#define OFF_WQ_PASS 204800
#define OFF_UH_SRC  307200
#define OFF_UH_WORD 1126400
#define OFF_UH_SENT 2437120
#define OFF_SC_SRC  2469888
#define OFF_SC_WORD 2549888
#define OFF_SC_SENT 2677888
// f32 region ends at float 2681088 = byte 10724352
// bf16 regions (byte offsets):
#define P_BYTE_OFF  10724352ull   // P[b][64][1056]  bf16 = 540672 B
#define MT_BYTE_OFF 11265024ull   // Mt[b][512][1056] bf16 = 4325376 B
#define WT_BYTE_OFF 15590400ull   // Wt[6][512][512] bf16 = 3145728 B (end ~18.74 MB)

__device__ __forceinline__ ushort_t f2b(float f) {
    __hip_bfloat16 h = __float2bfloat16(f);   // RNE
    return *(ushort_t*)&h;
}

// ---------------- k0f: fused transposes ----------------
// z=0..5: weight W[k][n] -> Wt[n][k] (x<16, y<16); z=6..9: banks -> Mt[b][d][s] (x<33, y<16)
__global__ __launch_bounds__(256) void k0f_transpose(
    const float* __restrict__ w0, const float* __restrict__ w1,
    const float* __restrict__ w2, const float* __restrict__ w3,
    const float* __restrict__ w4, const float* __restrict__ w5,
    const float* __restrict__ src_bank, const float* __restrict__ qa_word_bank,
    ushort_t* __restrict__ wt, ushort_t* __restrict__ mt)
{
    __shared__ float tile[32][33];
    int z = blockIdx.z;
    int tx = threadIdx.x & 31, ty = threadIdx.x >> 5;
    if (z < 6) {
        if (blockIdx.x >= 16) return;
        const float* W;
        switch (z) {
            case 0: W = w0; break; case 1: W = w1; break; case 2: W = w2; break;
            case 3: W = w3; break; case 4: W = w4; break; default: W = w5; break;
        }
        ushort_t* Wt = wt + z * (D_ * D_);
        int n0 = blockIdx.x * 32, k0 = blockIdx.y * 32;
#pragma unroll
        for (int a = 0; a < 4; ++a)
            tile[ty + a * 8][tx] = W[(k0 + ty + a * 8) * D_ + n0 + tx];
        __syncthreads();
#pragma unroll
        for (int a = 0; a < 4; ++a)
            Wt[(n0 + ty + a * 8) * D_ + k0 + tx] = f2b(tile[tx][ty + a * 8]);
    } else {
        int b = z - 6;
        int s0 = blockIdx.x * 32, d0 = blockIdx.y * 32;
#pragma unroll
        for (int a = 0; a < 4; ++a) {
            int s = s0 + ty + a * 8;
            float val = 0.f;
            if (s < SRC_) {
                val = src_bank[(s * B_ + b) * D_ + d0 + tx];
            } else if (s < NMEM_) {
                int j = s - SRC_; int se = j / WORDS_; int wd = j - se * WORDS_;
                val = qa_word_bank[((wd * B_ + b) * SENTS_ + se) * D_ + d0 + tx];
            }
            tile[ty + a * 8][tx] = val;
        }
        __syncthreads();
        ushort_t* base = mt + (size_t)b * D_ * NK_;
#pragma unroll
        for (int a = 0; a < 4; ++a) {
            int d = d0 + ty + a * 8;
            base[(size_t)d * NK_ + s0 + tx] = f2b(tile[tx][ty + a * 8]);
        }
    }
}

// ---------------- k1: all projections via bf16 MFMA, fp32*C2L2E out to ws ----------------
// grid (8 n-tiles, 40 m-tiles, 6 segments), 256 thr. Block tile 64x64, K=512.
__global__ __launch_bounds__(256) void k1_gemm(
    const float* __restrict__ source, const float* __restrict__ src_bank,
    const float* __restrict__ qa_sent_bank, const float* __restrict__ qa_word_bank,
    const ushort_t* __restrict__ wt,
    const float* __restrict__ bq_word, const float* __restrict__ bq_sent,
    const float* __restrict__ bq_pass,
    float* __restrict__ wsf)
{
    __shared__ short At[64 * 32];
    __shared__ short Bt[64 * 32];
    int z = blockIdx.z;
    int M, atype; const float* bias; float* C;
    switch (z) {
        case 0: M = 200;  atype = 0; bias = bq_word; C = wsf + OFF_WQ_WORD; break;
        case 1: M = 200;  atype = 0; bias = bq_sent; C = wsf + OFF_WQ_SENT; break;
        case 2: M = 200;  atype = 0; bias = bq_pass; C = wsf + OFF_WQ_PASS; break;
        case 3: M = 2560; atype = 1; bias = nullptr; C = wsf + OFF_UH_WORD; break;
        case 4: M = 1600; atype = 2; bias = nullptr; C = wsf + OFF_UH_SRC;  break;
        default: M = 64;  atype = 3; bias = nullptr; C = wsf + OFF_UH_SENT; break;
    }
    int m0 = blockIdx.y * 64;
    if (m0 >= M) return;
    int n0 = blockIdx.x * 64;
    const ushort_t* W = wt + z * (D_ * D_);   // Wt: [n][k] bf16

    int tid = threadIdx.x;
    int lane = tid & 63, wv = tid >> 6;
    int quad = lane >> 4, l16 = lane & 15;
    int sm = tid >> 2, koff = (tid & 3) * 8;  // staging: row sm, 8-elem chunk koff

    // A-row gather base (row -> global f32 pointer per segment type)
    const float* arow = nullptr;
    {
        int r = m0 + sm;
        if (r < M) {
            if (atype == 0) arow = source + r * D_;
            else if (atype == 1) { int b = r / NW_; int j = r - b * NW_;
                                   int se = j / WORDS_; int wd = j - se * WORDS_;
                                   arow = qa_word_bank + ((wd * B_ + b) * SENTS_ + se) * D_; }
            else if (atype == 2) { int b = r / SRC_; int j = r - b * SRC_;
                                   arow = src_bank + (j * B_ + b) * D_; }
            else                 { int b = r >> 4; int s2 = r & 15;
                                   arow = qa_sent_bank + (s2 * B_ + b) * D_; }
        }
    }
    const ushort_t* wrow = W + (n0 + sm) * D_;

    f4v acc[4] = { {0.f,0.f,0.f,0.f}, {0.f,0.f,0.f,0.f},
                   {0.f,0.f,0.f,0.f}, {0.f,0.f,0.f,0.f} };

    for (int kk = 0; kk < 16; ++kk) {
        int k0 = kk * 32;
        union { ushort_t u[8]; int4 v; } pk;
        if (arow) {
            float4 f0 = *(const float4*)(arow + k0 + koff);
            float4 f1 = *(const float4*)(arow + k0 + koff + 4);
            pk.u[0] = f2b(f0.x); pk.u[1] = f2b(f0.y);
            pk.u[2] = f2b(f0.z); pk.u[3] = f2b(f0.w);
            pk.u[4] = f2b(f1.x); pk.u[5] = f2b(f1.y);
            pk.u[6] = f2b(f1.z); pk.u[7] = f2b(f1.w);
        } else {
            pk.v = int4{0, 0, 0, 0};
        }
        int4 bv = *(const int4*)(wrow + k0 + koff);
        *(int4*)(At + sm * 32 + koff) = pk.v;
        *(int4*)(Bt + sm * 32 + koff) = bv;
        __syncthreads();
        s8v af = *(const s8v*)(At + (wv * 16 + l16) * 32 + quad * 8);
#pragma unroll
        for (int ng = 0; ng < 4; ++ng) {
            s8v bf = *(const s8v*)(Bt + (ng * 16 + l16) * 32 + quad * 8);
            acc[ng] = __builtin_amdgcn_mfma_f32_16x16x32_bf16(af, bf, acc[ng], 0, 0, 0);
        }
        __syncthreads();
    }
    // epilogue: D col = lane&15, row = quad*4 + r. Pre-scale by 2*log2e so
    // k2 can use exp2 directly: stored value = (acc+bias) * C2L2E.
#pragma unroll
    for (int ng = 0; ng < 4; ++ng) {
        int col = n0 + ng * 16 + l16;
        float bb = bias ? bias[col] : 0.f;
#pragma unroll
        for (int rr = 0; rr < 4; ++rr) {
            int row = m0 + wv * 16 + quad * 4 + rr;
            if (row < M) C[row * D_ + col] = (acc[ng][rr] + bb) * C2L2E;
        }
    }
}

// ---------------- k2: additive-attention scores ----------------
// 2 waves per (b,slot) job (25 t each). Masked jobs (never read by k3a) exit
// immediately. score = Vsum - 2*sum_d v[d]*sigmoid(-2x); exp(2x)=exp2(pre-scaled).
__global__ __launch_bounds__(256) void k2_scores(
    const float* __restrict__ v_word, const float* __restrict__ v_sent,
    const float* __restrict__ v_pass,
    const int* __restrict__ src_lengths, const int* __restrict__ qa_word_lengths,
    float* __restrict__ wsf)
{
    int lane = threadIdx.x & 63;
    int job2 = blockIdx.x * 4 + (threadIdx.x >> 6);   // 8448 job-halves, exact
    int job = job2 >> 1, th = job2 & 1;
    int b = job / NJOB_, slot = job - b * NJOB_;
    const float* uh; const float* v; const float* wq; float* out; int ostride;
    if (slot < SRC_) {
        if (slot >= src_lengths[b]) return;           // masked: value never read
        uh = wsf + OFF_UH_SRC + (b * SRC_ + slot) * D_;
        v = v_pass; wq = wsf + OFF_WQ_PASS + b * T_ * D_;
        out = wsf + OFF_SC_SRC + b * T_ * SRC_ + slot; ostride = SRC_;
    } else if (slot < NMEM_) {
        int j = slot - SRC_;
        int se = j / WORDS_; int wd = j - se * WORDS_;
        if (wd >= qa_word_lengths[b * SENTS_ + se]) return;  // masked
        uh = wsf + OFF_UH_WORD + (b * NW_ + j) * D_;
        v = v_word; wq = wsf + OFF_WQ_WORD + b * T_ * D_;
        out = wsf + OFF_SC_WORD + b * T_ * NW_ + j; ostride = NW_;
    } else {
        int s2 = slot - NMEM_;
        uh = wsf + OFF_UH_SENT + (b * SENTS_ + s2) * D_;
        v = v_sent; wq = wsf + OFF_WQ_SENT + b * T_ * D_;
        out = wsf + OFF_SC_SENT + b * T_ * SENTS_ + s2; ostride = SENTS_;
    }
    int d0 = lane * 8;
    float4 u0 = *(const float4*)(uh + d0);
    float4 u1 = *(const float4*)(uh + d0 + 4);
    float uhr[8] = {u0.x, u0.y, u0.z, u0.w, u1.x, u1.y, u1.z, u1.w};
    float4 v0 = *(const float4*)(v + d0);
    float4 v1 = *(const float4*)(v + d0 + 4);
    float vr[8] = {v0.x, v0.y, v0.z, v0.w, v1.x, v1.y, v1.z, v1.w};

    // Vsum = sum_d v[d] (broadcast to all lanes)
    float vs = ((vr[0] + vr[1]) + (vr[2] + vr[3])) + ((vr[4] + vr[5]) + (vr[6] + vr[7]));
#pragma unroll
    for (int off = 32; off > 0; off >>= 1) vs += __shfl_xor(vs, off, 64);

    const float* wqh = wq + th * 25 * D_;
    float acc[25];
#pragma unroll 1
    for (int c = 0; c < 5; ++c) {
#pragma unroll
        for (int u5 = 0; u5 < 5; ++u5) {
            int u = c * 5 + u5;
            const float* wr = wqh + u * D_ + d0;
            float4 w0 = *(const float4*)(wr);
            float4 w1 = *(const float4*)(wr + 4);
            float wrr[8] = {w0.x, w0.y, w0.z, w0.w, w1.x, w1.y, w1.z, w1.w};
            float a = 0.f;
#pragma unroll
            for (int j = 0; j < 8; ++j) {
                float e = __builtin_amdgcn_exp2f(wrr[j] + uhr[j]);  // exp(2x)
                float r = __builtin_amdgcn_rcpf(e + 1.f);           // sigmoid(-2x)
                a = fmaf(vr[j], r, a);
            }
            acc[u] = a;
        }
    }
    // 25 independent butterfly reductions (latency overlapped)
#pragma unroll
    for (int off = 32; off > 0; off >>= 1) {
#pragma unroll
        for (int u = 0; u < 25; ++u)
            acc[u] += __shfl_xor(acc[u], off, 64);
    }
    if (lane == 0) {
#pragma unroll
        for (int u = 0; u < 25; ++u)
            out[(th * 25 + u) * ostride] = fmaf(-2.f, acc[u], vs);
    }
}

// ---------------- k3a: hier combine + mask + softmax -> bf16 P[b][64][1056] ----------------
__global__ __launch_bounds__(256) void k3a_softmax(
    const int* __restrict__ src_lengths, const int* __restrict__ qa_word_lengths,
    const float* __restrict__ wsf, ushort_t* __restrict__ P)
{
    __shared__ float p[NMEM_];
    __shared__ float red[4];
    int tid = threadIdx.x, lane = tid & 63, wv = tid >> 6;
    int bt = blockIdx.x, b = bt / T_, t = bt - b * T_;
    const float* sc_src  = wsf + OFF_SC_SRC  + bt * SRC_;
    const float* sc_word = wsf + OFF_SC_WORD + bt * NW_;
    const float* sc_sent = wsf + OFF_SC_SENT + bt * SENTS_;
    int slen = src_lengths[b];
    float mx = -3.0e38f;
    for (int j = tid; j < NMEM_; j += 256) {
        float val;
        if (j < SRC_) {
            val = (j < slen) ? sc_src[j] : -1e30f;
        } else {
            int jj = j - SRC_; int se = jj / WORDS_; int wd = jj - se * WORDS_;
            float raw = sc_word[jj] * sc_sent[se];
            val = (wd < qa_word_lengths[b * SENTS_ + se]) ? raw : -1e30f;
        }
        p[j] = val;
        mx = fmaxf(mx, val);
    }
#pragma unroll
    for (int off = 32; off > 0; off >>= 1) mx = fmaxf(mx, __shfl_xor(mx, off, 64));
    if (lane == 0) red[wv] = mx;
    __syncthreads();
    mx = fmaxf(fmaxf(red[0], red[1]), fmaxf(red[2], red[3]));
    __syncthreads();
    float lsum = 0.f;
    for (int j = tid; j < NMEM_; j += 256) {
        float e = __expf(p[j] - mx);
        p[j] = e; lsum += e;
    }
#pragma unroll
    for (int off = 32; off > 0; off >>= 1) lsum += __shfl_xor(lsum, off, 64);
    if (lane == 0) red[wv] = lsum;
    __syncthreads();
    float inv = 1.f / (red[0] + red[1] + red[2] + red[3]);
    ushort_t* prow = P + (size_t)(b * 64 + t) * NK_;
    for (int j = tid; j < NK_; j += 256)
        prow[j] = (j < NMEM_) ? f2b(p[j] * inv) : (ushort_t)0;
}

// ---------------- k3c: context GEMM  C[b][t][d] = sum_s P[t,s] * Mt[d,s] ----------------
// grid (16 d-tiles, 4 b), 256 thr. Tile 64(t,pad) x 32(d), K=1056.
__global__ __launch_bounds__(256) void k3c_gemm(
    const ushort_t* __restrict__ P, const ushort_t* __restrict__ Mt,
    float* __restrict__ out)
{
    __shared__ short At[64 * 32];
    __shared__ short Bt[32 * 32];
    int b = blockIdx.y;
    int n0 = blockIdx.x * 32;
    int tid = threadIdx.x;
    int lane = tid & 63, wv = tid >> 6;
    int quad = lane >> 4, l16 = lane & 15;
    int smA = tid >> 2, koffA = (tid & 3) * 8;   // A: 64 rows x 32k, int4/thread
    int smB = tid >> 3, koffB = (tid & 7) * 4;   // B: 32 rows x 32k, int2/thread

    const ushort_t* arow = P + (size_t)(b * 64 + smA) * NK_ + koffA;
    const ushort_t* brow = Mt + ((size_t)(b * D_ + n0 + smB)) * NK_ + koffB;

    f4v acc[2] = { {0.f,0.f,0.f,0.f}, {0.f,0.f,0.f,0.f} };

    for (int kk = 0; kk < 33; ++kk) {
        int k0 = kk * 32;
        int4 av = *(const int4*)(arow + k0);
        int2 bv = *(const int2*)(brow + k0);
        *(int4*)(At + smA * 32 + koffA) = av;
        *(int2*)(Bt + smB * 32 + koffB) = bv;
        __syncthreads();
        s8v af = *(const s8v*)(At + (wv * 16 + l16) * 32 + quad * 8);
#pragma unroll
        for (int ng = 0; ng < 2; ++ng) {
            s8v bf = *(const s8v*)(Bt + (ng * 16 + l16) * 32 + quad * 8);
            acc[ng] = __builtin_amdgcn_mfma_f32_16x16x32_bf16(af, bf, acc[ng], 0, 0, 0);
        }
        __syncthreads();
    }
#pragma unroll
    for (int ng = 0; ng < 2; ++ng) {
        int col = n0 + ng * 16 + l16;
#pragma unroll
        for (int rr = 0; rr < 4; ++rr) {
            int row = wv * 16 + quad * 4 + rr;   // t
            if (row < T_) out[(size_t)(b * T_ + row) * D_ + col] = acc[ng][rr];
        }
    }
}

extern "C" void kernel_launch(void* const* d_in, const int* in_sizes, int n_in,
                              void* d_out, int out_size, void* d_ws, size_t ws_size,
                              hipStream_t stream)
{
    (void)in_sizes; (void)n_in; (void)out_size; (void)ws_size;
    const float* source          = (const float*)d_in[0];
    const float* src_bank        = (const float*)d_in[1];
    const int*   src_lengths     = (const int*)d_in[2];
    const float* qa_sent_bank    = (const float*)d_in[3];
    /* d_in[4] qa_sent_lengths unused (matches reference) */
    const float* qa_word_bank    = (const float*)d_in[5];
    const int*   qa_word_lengths = (const int*)d_in[6];
    const float* Wq_word = (const float*)d_in[7];
    const float* bq_word = (const float*)d_in[8];
    const float* Uc_word = (const float*)d_in[9];
    const float* v_word  = (const float*)d_in[10];
    const float* Wq_sent = (const float*)d_in[11];
    const float* bq_sent = (const float*)d_in[12];
    const float* Uc_sent = (const float*)d_in[13];
    const float* v_sent  = (const float*)d_in[14];
    const float* Wq_pass = (const float*)d_in[15];
    const float* bq_pass = (const float*)d_in[16];
    const float* Uc_pass = (const float*)d_in[17];
    const float* v_pass  = (const float*)d_in[18];

    float* wsf = (float*)d_ws;
    ushort_t* Pb  = (ushort_t*)((char*)d_ws + P_BYTE_OFF);
    ushort_t* mt  = (ushort_t*)((char*)d_ws + MT_BYTE_OFF);
    ushort_t* wt  = (ushort_t*)((char*)d_ws + WT_BYTE_OFF);
    float* out = (float*)d_out;

    // Wt slot order must match k1 segment order:
    // 0:Wq_word 1:Wq_sent 2:Wq_pass 3:Uc_word 4:Uc_pass 5:Uc_sent ; z=6..9 banks
    k0f_transpose<<<dim3(33, 16, 10), dim3(256), 0, stream>>>(
        Wq_word, Wq_sent, Wq_pass, Uc_word, Uc_pass, Uc_sent,
        src_bank, qa_word_bank, wt, mt);
    k1_gemm<<<dim3(8, 40, 6), dim3(256), 0, stream>>>(
        source, src_bank, qa_sent_bank, qa_word_bank, wt,
        bq_word, bq_sent, bq_pass, wsf);
    k2_scores<<<dim3(NJOB_ * 2), dim3(256), 0, stream>>>(
        v_word, v_sent, v_pass, src_lengths, qa_word_lengths, wsf);
    k3a_softmax<<<dim3(200), dim3(256), 0, stream>>>(src_lengths, qa_word_lengths, wsf, Pb);
    k3c_gemm<<<dim3(16, 4), dim3(256), 0, stream>>>(Pb, mt, out);
}